// Round 1
// baseline (13852.252 us; speedup 1.0000x reference)
//
#include <hip/hip_runtime.h>
#include <math.h>

// Problem dims
#define T_DIM 1024
#define NP    2048
#define NB    1024           // batch*joints = 16*64
#define NITER 25
#define NSQ   6              // squarings: M ~ G^64
#define NPI   32             // power iterations on squared matrix
#define LAM0  0.1f
#define EPS_W 1e-10f

// GEMM tiling: 128x64 tile, BK=16, 128 threads, 8x8 micro-tile
#define BM 128
#define BN 64
#define BK 16
#define NT 128

// Core GEMM: acc[8][8] += A_tile^(sym-as-[k][m]) * B_tile.
// As[k][m] = A[(k0+k)*lda + m0+m]  (valid when A symmetric, or A physically [k][m])
// Bs[k][n] = B[(k0+k)*ldb + n0+n]
__device__ __forceinline__ void gemm_core(
    const float* __restrict__ A, int lda,
    const float* __restrict__ B, int ldb,
    int K, int m0, int n0, float acc[8][8])
{
  __shared__ float As[BK][BM];
  __shared__ float Bs[BK][BN];
  const int tid = threadIdx.x;
  const int tx = tid & 7;
  const int ty = tid >> 3;
#pragma unroll
  for (int i = 0; i < 8; i++)
#pragma unroll
    for (int j = 0; j < 8; j++) acc[i][j] = 0.f;

  for (int k0 = 0; k0 < K; k0 += BK) {
    // A tile: BK x BM = 2048 floats = 512 float4, 4 per thread
#pragma unroll
    for (int i = 0; i < 4; i++) {
      int L = tid + i * NT;          // 0..511
      int kk = L >> 5;               // 0..15
      int c4 = L & 31;               // 0..31
      float4 v = *(const float4*)(A + (size_t)(k0 + kk) * lda + m0 + c4 * 4);
      *(float4*)(&As[kk][c4 * 4]) = v;
    }
    // B tile: BK x BN = 1024 floats = 256 float4, 2 per thread
#pragma unroll
    for (int i = 0; i < 2; i++) {
      int L = tid + i * NT;          // 0..255
      int kk = L >> 4;               // 0..15
      int c4 = L & 15;               // 0..15
      float4 v = *(const float4*)(B + (size_t)(k0 + kk) * ldb + n0 + c4 * 4);
      *(float4*)(&Bs[kk][c4 * 4]) = v;
    }
    __syncthreads();
#pragma unroll
    for (int kk = 0; kk < BK; kk++) {
      float a[8], b[8];
      *(float4*)&a[0] = *(const float4*)&As[kk][ty * 8];
      *(float4*)&a[4] = *(const float4*)&As[kk][ty * 8 + 4];
      *(float4*)&b[0] = *(const float4*)&Bs[kk][tx * 8];
      *(float4*)&b[4] = *(const float4*)&Bs[kk][tx * 8 + 4];
#pragma unroll
      for (int i = 0; i < 8; i++)
#pragma unroll
        for (int j = 0; j < 8; j++)
          acc[i][j] = fmaf(a[i], b[j], acc[i][j]);
    }
    __syncthreads();
  }
}

// DtD[p][q] = sum_t D[t][p] D[t][q]   (M=N=2048, K=1024)
__global__ __launch_bounds__(NT) void k_dtd(const float* __restrict__ D, float* __restrict__ DtD) {
  float acc[8][8];
  const int m0 = blockIdx.x * BM, n0 = blockIdx.y * BN;
  gemm_core(D, NP, D, NP, T_DIM, m0, n0, acc);
  const int tid = threadIdx.x, tx = tid & 7, ty = tid >> 3;
#pragma unroll
  for (int i = 0; i < 8; i++) {
    const int m = m0 + ty * 8 + i;
    float* o = DtD + (size_t)m * NP + n0 + tx * 8;
    *(float4*)(o)     = make_float4(acc[i][0], acc[i][1], acc[i][2], acc[i][3]);
    *(float4*)(o + 4) = make_float4(acc[i][4], acc[i][5], acc[i][6], acc[i][7]);
  }
}

// G[s][t] = sum_p D[s][p] D[t][p]  (M=N=1024, K=2048) — needs transpose-on-store tiles.
// Also accumulates ss0 = ||G||_F^2.
__global__ __launch_bounds__(NT) void k_g(const float* __restrict__ D, float* __restrict__ G,
                                          float* __restrict__ ss0) {
  __shared__ float As[BK][BM + 4];
  __shared__ float Bs[BK][BN + 4];
  const int tid = threadIdx.x;
  const int tx = tid & 7, ty = tid >> 3;
  const int m0 = blockIdx.x * BM, n0 = blockIdx.y * BN;
  float acc[8][8];
#pragma unroll
  for (int i = 0; i < 8; i++)
#pragma unroll
    for (int j = 0; j < 8; j++) acc[i][j] = 0.f;

  for (int k0 = 0; k0 < NP; k0 += BK) {
#pragma unroll
    for (int i = 0; i < 4; i++) {
      int L = tid + i * NT; int r = L >> 2; int c4 = L & 3;
      float4 v = *(const float4*)(D + (size_t)(m0 + r) * NP + k0 + c4 * 4);
      As[c4 * 4 + 0][r] = v.x; As[c4 * 4 + 1][r] = v.y;
      As[c4 * 4 + 2][r] = v.z; As[c4 * 4 + 3][r] = v.w;
    }
#pragma unroll
    for (int i = 0; i < 2; i++) {
      int L = tid + i * NT; int r = L >> 2; int c4 = L & 3;
      float4 v = *(const float4*)(D + (size_t)(n0 + r) * NP + k0 + c4 * 4);
      Bs[c4 * 4 + 0][r] = v.x; Bs[c4 * 4 + 1][r] = v.y;
      Bs[c4 * 4 + 2][r] = v.z; Bs[c4 * 4 + 3][r] = v.w;
    }
    __syncthreads();
#pragma unroll
    for (int kk = 0; kk < BK; kk++) {
      float a[8], b[8];
      *(float4*)&a[0] = *(const float4*)&As[kk][ty * 8];
      *(float4*)&a[4] = *(const float4*)&As[kk][ty * 8 + 4];
      *(float4*)&b[0] = *(const float4*)&Bs[kk][tx * 8];
      *(float4*)&b[4] = *(const float4*)&Bs[kk][tx * 8 + 4];
#pragma unroll
      for (int i = 0; i < 8; i++)
#pragma unroll
        for (int j = 0; j < 8; j++)
          acc[i][j] = fmaf(a[i], b[j], acc[i][j]);
    }
    __syncthreads();
  }
  float ssl = 0.f;
#pragma unroll
  for (int i = 0; i < 8; i++) {
    const int m = m0 + ty * 8 + i;
    float* o = G + (size_t)m * 1024 + n0 + tx * 8;
    *(float4*)(o)     = make_float4(acc[i][0], acc[i][1], acc[i][2], acc[i][3]);
    *(float4*)(o + 4) = make_float4(acc[i][4], acc[i][5], acc[i][6], acc[i][7]);
#pragma unroll
    for (int j = 0; j < 8; j++) ssl = fmaf(acc[i][j], acc[i][j], ssl);
  }
  __syncthreads();
  float* red = &As[0][0];
  red[tid] = ssl; __syncthreads();
  for (int off = NT / 2; off > 0; off >>= 1) {
    if (tid < off) red[tid] += red[tid + off];
    __syncthreads();
  }
  if (tid == 0) atomicAdd(ss0, red[0]);
}

// DtY[p][n] = sum_t D[t][p] * Y[b][t][j], n = b*64+j. BN=64 aligns with one batch b.
__global__ __launch_bounds__(NT) void k_dty(const float* __restrict__ D, const float* __restrict__ Y,
                                            float* __restrict__ DtY) {
  float acc[8][8];
  const int m0 = blockIdx.x * BM, n0 = blockIdx.y * BN;
  const int b = n0 >> 6;
  const float* Bptr = Y + (size_t)b * T_DIM * 64;   // [t][j], ld 64
  gemm_core(D, NP, Bptr, 64, T_DIM, m0, 0, acc);
  const int tid = threadIdx.x, tx = tid & 7, ty = tid >> 3;
#pragma unroll
  for (int i = 0; i < 8; i++) {
    const int m = m0 + ty * 8 + i;
    float* o = DtY + (size_t)m * NB + n0 + tx * 8;
    *(float4*)(o)     = make_float4(acc[i][0], acc[i][1], acc[i][2], acc[i][3]);
    *(float4*)(o + 4) = make_float4(acc[i][4], acc[i][5], acc[i][6], acc[i][7]);
  }
}

// Mout = (Min @ Min) / ssPrev  (Min symmetric, 1024^2); accumulates ssNext = ||Mout||_F^2
__global__ __launch_bounds__(NT) void k_sq(const float* __restrict__ Min, float* __restrict__ Mout,
                                           const float* __restrict__ ssPrev, float* __restrict__ ssNext) {
  float acc[8][8];
  const int m0 = blockIdx.x * BM, n0 = blockIdx.y * BN;
  gemm_core(Min, 1024, Min, 1024, 1024, m0, n0, acc);
  const float inv = 1.0f / ssPrev[0];
  const int tid = threadIdx.x, tx = tid & 7, ty = tid >> 3;
  float ssl = 0.f;
#pragma unroll
  for (int i = 0; i < 8; i++) {
    const int m = m0 + ty * 8 + i;
    float o[8];
#pragma unroll
    for (int j = 0; j < 8; j++) { o[j] = acc[i][j] * inv; ssl = fmaf(o[j], o[j], ssl); }
    float* op = Mout + (size_t)m * 1024 + n0 + tx * 8;
    *(float4*)(op)     = make_float4(o[0], o[1], o[2], o[3]);
    *(float4*)(op + 4) = make_float4(o[4], o[5], o[6], o[7]);
  }
  __shared__ float red[NT];
  red[tid] = ssl; __syncthreads();
  for (int off = NT / 2; off > 0; off >>= 1) {
    if (tid < off) red[tid] += red[tid + off];
    __syncthreads();
  }
  if (tid == 0) atomicAdd(ssNext, red[0]);
}

// X init: deterministic hash noise in [-0.5, 0.5], 1024x4
__global__ void k_initx(float* __restrict__ X) {
  int g = blockIdx.x * 256 + threadIdx.x;
  if (g < 4096) {
    unsigned h = (unsigned)g * 2654435761u;
    h ^= h >> 16; h *= 2246822519u; h ^= h >> 13;
    X[g] = ((float)(h & 0xffffff) / 16777216.0f) - 0.5f;
  }
}

// One block power step on M (1024^2, symmetric), 4 columns, lazy normalization.
__global__ __launch_bounds__(256) void k_matvec(const float* __restrict__ M, const float* __restrict__ Xin,
                                                float* __restrict__ Xout, const float* __restrict__ prevNorm,
                                                float* __restrict__ outNorm) {
  const int tid = threadIdx.x;
  const int row = blockIdx.x * 64 + (tid >> 2);
  const int c = tid & 3;
  const float scale = prevNorm ? rsqrtf(prevNorm[c]) : 1.0f;
  const float* Mr = M + (size_t)row * 1024;
  float s0 = 0, s1 = 0, s2 = 0, s3 = 0;
  for (int k = 0; k < 1024; k += 4) {
    s0 = fmaf(Mr[k],     Xin[(k) * 4 + c],     s0);
    s1 = fmaf(Mr[k + 1], Xin[(k + 1) * 4 + c], s1);
    s2 = fmaf(Mr[k + 2], Xin[(k + 2) * 4 + c], s2);
    s3 = fmaf(Mr[k + 3], Xin[(k + 3) * 4 + c], s3);
  }
  float s = ((s0 + s1) + (s2 + s3)) * scale;
  Xout[row * 4 + c] = s;
  __shared__ float red[256];
  red[tid] = s * s; __syncthreads();
  for (int off = 128; off >= 4; off >>= 1) {
    if (tid < off) red[tid] += red[tid + off];
    __syncthreads();
  }
  if (tid < 4) atomicAdd(&outNorm[tid], red[tid]);
}

// Rayleigh quotient of each of 4 columns against the ORIGINAL G
__global__ __launch_bounds__(256) void k_rq(const float* __restrict__ G, const float* __restrict__ X,
                                            float* __restrict__ num, float* __restrict__ den) {
  const int tid = threadIdx.x;
  const int row = blockIdx.x * 64 + (tid >> 2);
  const int c = tid & 3;
  const float v = X[row * 4 + c];
  const float* Gr = G + (size_t)row * 1024;
  float s0 = 0, s1 = 0, s2 = 0, s3 = 0;
  for (int k = 0; k < 1024; k += 4) {
    s0 = fmaf(Gr[k],     X[(k) * 4 + c],     s0);
    s1 = fmaf(Gr[k + 1], X[(k + 1) * 4 + c], s1);
    s2 = fmaf(Gr[k + 2], X[(k + 2) * 4 + c], s2);
    s3 = fmaf(Gr[k + 3], X[(k + 3) * 4 + c], s3);
  }
  float w = (s0 + s1) + (s2 + s3);
  __shared__ float rn[256], rd[256];
  rn[tid] = v * w; rd[tid] = v * v; __syncthreads();
  for (int off = 128; off >= 4; off >>= 1) {
    if (tid < off) { rn[tid] += rn[tid + off]; rd[tid] += rd[tid + off]; }
    __syncthreads();
  }
  if (tid < 4) { atomicAdd(&num[tid], rn[tid]); atomicAdd(&den[tid], rd[tid]); }
}

__global__ void k_finL(const float* __restrict__ num, const float* __restrict__ den, float* __restrict__ Lout) {
  if (threadIdx.x == 0 && blockIdx.x == 0) {
    float best = 0.f;
    for (int c = 0; c < 4; c++) { float r = num[c] / den[c]; best = fmaxf(best, r); }
    Lout[0] = 1.0f / best;
  }
}

// Fused FISTA step: acc = DtD @ CpIn; grad = acc - DtY; z = Cp - L*grad;
// Cn = soft(z, thr); Cp' = Cn + tc*(Cn - Cc).
__global__ __launch_bounds__(NT) void k_main(const float* __restrict__ DtD_, const float* __restrict__ CpIn,
                                             const float* __restrict__ CcIn, const float* __restrict__ DtY_,
                                             const float* __restrict__ Lptr, const float* __restrict__ thrMat,
                                             float tc, float* __restrict__ CcOut, float* __restrict__ CpOut) {
  float acc[8][8];
  const int m0 = blockIdx.x * BM, n0 = blockIdx.y * BN;
  gemm_core(DtD_, NP, CpIn, NB, NP, m0, n0, acc);
  const float Lv = Lptr[0];
  const float thr_s = LAM0 * Lv;
  const int tid = threadIdx.x, tx = tid & 7, ty = tid >> 3;
#pragma unroll
  for (int i = 0; i < 8; i++) {
    const int m = m0 + ty * 8 + i;
    const size_t base = (size_t)m * NB + n0 + tx * 8;
    float dty[8], cp[8], cc[8], th[8];
    *(float4*)&dty[0] = *(const float4*)(DtY_ + base);
    *(float4*)&dty[4] = *(const float4*)(DtY_ + base + 4);
    *(float4*)&cp[0]  = *(const float4*)(CpIn + base);
    *(float4*)&cp[4]  = *(const float4*)(CpIn + base + 4);
    *(float4*)&cc[0]  = *(const float4*)(CcIn + base);
    *(float4*)&cc[4]  = *(const float4*)(CcIn + base + 4);
    if (thrMat) {
      *(float4*)&th[0] = *(const float4*)(thrMat + base);
      *(float4*)&th[4] = *(const float4*)(thrMat + base + 4);
    }
    float cn[8], cpn[8];
#pragma unroll
    for (int j = 0; j < 8; j++) {
      float grad = acc[i][j] - dty[j];
      float z = cp[j] - Lv * grad;
      float t2 = thrMat ? th[j] : thr_s;
      float az = fabsf(z) - t2;
      float v = az > 0.f ? copysignf(az, z) : 0.f;
      cn[j] = v;
      cpn[j] = fmaf(tc, v - cc[j], v);
    }
    *(float4*)(CcOut + base)     = make_float4(cn[0], cn[1], cn[2], cn[3]);
    *(float4*)(CcOut + base + 4) = make_float4(cn[4], cn[5], cn[6], cn[7]);
    *(float4*)(CpOut + base)     = make_float4(cpn[0], cpn[1], cpn[2], cpn[3]);
    *(float4*)(CpOut + base + 4) = make_float4(cpn[4], cpn[5], cpn[6], cpn[7]);
  }
}

// colss[n] = sum_p (1/(|Cc[p][n]|+eps))^2 ; 64 blocks x 16 cols
__global__ __launch_bounds__(256) void k_colss(const float* __restrict__ Cc, float* __restrict__ colss) {
  const int tid = threadIdx.x;
  const int c = blockIdx.x * 16 + (tid & 15);
  const int pg = tid >> 4;
  float s = 0.f;
  for (int p = pg; p < NP; p += 16) {
    float r = 1.0f / (fabsf(Cc[(size_t)p * NB + c]) + EPS_W);
    s = fmaf(r, r, s);
  }
  __shared__ float red[256];
  red[tid] = s; __syncthreads();
  for (int off = 128; off >= 16; off >>= 1) {
    if (tid < off) red[tid] += red[tid + off];
    __syncthreads();
  }
  if (tid < 16) colss[blockIdx.x * 16 + tid] = red[tid];
}

// thrMat = L * 0.1 * Np * r / sqrt(colss[n]),  r = 1/(|Cc|+eps)
__global__ __launch_bounds__(256) void k_thrmat(const float* __restrict__ Cc, const float* __restrict__ colss,
                                                const float* __restrict__ Lptr, float* __restrict__ thrMat) {
  const size_t g = (size_t)blockIdx.x * 256 + threadIdx.x;
  const int n = (int)(g & (NB - 1));
  float r = 1.0f / (fabsf(Cc[g]) + EPS_W);
  thrMat[g] = Lptr[0] * LAM0 * (float)NP * r * rsqrtf(colss[n]);
}

// out[b][p][j] = C[p][b*64+j]
__global__ __launch_bounds__(256) void k_out(const float* __restrict__ Cc, float* __restrict__ out) {
  const size_t g = (size_t)blockIdx.x * 256 + threadIdx.x;
  const int p = (int)(g >> 10);
  const int n = (int)(g & 1023);
  out[(size_t)(n >> 6) * (NP * 64) + (size_t)p * 64 + (n & 63)] = Cc[g];
}

extern "C" void kernel_launch(void* const* d_in, const int* in_sizes, int n_in,
                              void* d_out, int out_size, void* d_ws, size_t ws_size,
                              hipStream_t stream) {
  const float* Y = (const float*)d_in[0];   // [16,1024,64]
  const float* D = (const float*)d_in[1];   // [1024,2048]
  float* out = (float*)d_out;
  float* ws = (float*)d_ws;

  float* DtD  = ws;                                    // 2048*2048
  float* DtY  = DtD + (size_t)NP * NP;                 // 2048*1024
  float* Cc0  = DtY + (size_t)NP * NB;
  float* Cc1  = Cc0 + (size_t)NP * NB;
  float* Cp0  = Cc1 + (size_t)NP * NB;
  float* Cp1  = Cp0 + (size_t)NP * NB;
  float* thrM = Cp1 + (size_t)NP * NB;
  float* G    = thrM + (size_t)NP * NB;                // 1024*1024
  float* S0   = G  + (size_t)1024 * 1024;
  float* S1   = S0 + (size_t)1024 * 1024;
  float* XA   = S1 + (size_t)1024 * 1024;              // 4096
  float* XB   = XA + 4096;
  float* scal = XB + 4096;    // ss[8] | norms[NPI*4] | num[4] | den[4] | L[1] | colss[1024]
  float* ssv   = scal;
  float* norms = scal + 8;
  float* num   = scal + 8 + NPI * 4;
  float* den   = num + 4;
  float* Lp    = den + 4;
  float* colss = Lp + 4;

  float* CcB[2] = {Cc0, Cc1};
  float* CpB[2] = {Cp0, Cp1};

  hipMemsetAsync(Cc0, 0, (size_t)NP * NB * sizeof(float), stream);
  hipMemsetAsync(Cp0, 0, (size_t)NP * NB * sizeof(float), stream);
  hipMemsetAsync(scal, 0, (8 + NPI * 4 + 16) * sizeof(float), stream);

  dim3 blk(NT);
  k_initx<<<16, 256, 0, stream>>>(XA);
  k_dtd<<<dim3(NP / BM, NP / BN), blk, 0, stream>>>(D, DtD);
  k_g  <<<dim3(1024 / BM, 1024 / BN), blk, 0, stream>>>(D, G, ssv);
  k_dty<<<dim3(NP / BM, NB / BN), blk, 0, stream>>>(D, Y, DtY);

  const float* sq[7] = {G, S0, S1, S0, S1, S0, S1};
  for (int l = 0; l < NSQ; l++)
    k_sq<<<dim3(1024 / BM, 1024 / BN), blk, 0, stream>>>(sq[l], (float*)sq[l + 1], ssv + l, ssv + l + 1);

  const float* Mfin = sq[NSQ];  // S1
  for (int i = 0; i < NPI; i++) {
    const float* xin = (i & 1) ? XB : XA;
    float* xout = (i & 1) ? XA : XB;
    k_matvec<<<16, 256, 0, stream>>>(Mfin, xin, xout,
                                     i ? norms + (i - 1) * 4 : nullptr, norms + i * 4);
  }
  // NPI even -> final vector in XA
  k_rq  <<<16, 256, 0, stream>>>(G, XA, num, den);
  k_finL<<<1, 64, 0, stream>>>(num, den, Lp);

  // deterministic t-sequence (done-flag can never trigger: ||dC||_F >> 1e-6)
  float tcv[2 * NITER];
  {
    float t = 1.0f;
    for (int i = 0; i < 2 * NITER; i++) {
      float tn = 0.5f * (1.0f + sqrtf(1.0f + 4.0f * t * t));
      tcv[i] = (t - 1.0f) / tn;
      t = tn;
    }
  }

  for (int i = 0; i < 2 * NITER; i++) {
    if (i == NITER) {
      k_colss <<<64, 256, 0, stream>>>(CcB[NITER & 1], colss);
      k_thrmat<<<(NP * NB) / 256, 256, 0, stream>>>(CcB[NITER & 1], colss, Lp, thrM);
    }
    const float* thr = (i < NITER) ? nullptr : thrM;
    int a = i & 1, b = (i + 1) & 1;
    k_main<<<dim3(NP / BM, NB / BN), blk, 0, stream>>>(DtD, CpB[a], CcB[a], DtY, Lp, thr,
                                                       tcv[i], CcB[b], CpB[b]);
  }
  // 50 iterations -> final state in buffer 0
  k_out<<<(NP * NB) / 256, 256, 0, stream>>>(CcB[0], out);
}

// Round 3
// 4060.363 us; speedup vs baseline: 3.4116x; 3.4116x over previous
//
#include <hip/hip_runtime.h>
#include <math.h>

#define T_DIM 1024
#define NP    2048
#define NB    1024
#define NITER 25
#define NSQ   7
#define NPI   8
#define LAM0  0.1f
#define EPS_W 1e-10f

typedef float    f32x4 __attribute__((ext_vector_type(4)));
typedef _Float16 f16x8 __attribute__((ext_vector_type(8)));
typedef _Float16 f16x4 __attribute__((ext_vector_type(4)));

__device__ __forceinline__ void gload16(const void* g, void* l) {
  __builtin_amdgcn_global_load_lds((const __attribute__((address_space(1))) unsigned int*)g,
                                   (__attribute__((address_space(3))) unsigned int*)l, 16, 0, 0);
}

// =====================================================================
// Dual-accumulator 3-pass split-f16 GEMM core.
// out = (Ah + Al/4096) x (Bh + Bl/4096)^T-ish: A[n][k], B[p][k], both ld=ldk.
// acc0 = Ah.Bh ; acc1 = Al.Bh + Ah.Bl (scale 2^12); result acc0 + acc1/4096.
// 512 threads = 8 waves, block tile 128(n) x 128(p), wave tile 64x32.
// =====================================================================
__device__ __forceinline__ void mm3_core(
    const _Float16* __restrict__ Ah, const _Float16* __restrict__ Al,
    const _Float16* __restrict__ Bh, const _Float16* __restrict__ Bl,
    int ldk, int n0, int p0, int kb0, int nsteps,
    f32x4 acc0[4][2], f32x4 acc1[4][2])
{
  __shared__ __align__(16) _Float16 sAh[8192], sAl[8192], sBh[8192], sBl[8192];
  const int tid = threadIdx.x;
  const int lane = tid & 63, wave = tid >> 6;
  const int quad = lane >> 4, rl = lane & 15;
#pragma unroll
  for (int i = 0; i < 4; i++)
#pragma unroll
    for (int j = 0; j < 2; j++) { acc0[i][j] = (f32x4)0.0f; acc1[i][j] = (f32x4)0.0f; }
  const int wn = (wave >> 2) * 64, wp = (wave & 3) * 32;

  for (int s = 0; s < nsteps; s++) {
    const int kb = kb0 + s * 64;
    if (s) __syncthreads();
#pragma unroll
    for (int i = 0; i < 2; i++) {
      int slot = i * 512 + wave * 64 + lane;
      int kc = slot >> 7, row = slot & 127;
      int lb = (i * 512 + wave * 64) * 8;     // wave-uniform LDS base (elements)
      size_t ga = (size_t)(n0 + row) * ldk + kb + kc * 8;
      size_t gb = (size_t)(p0 + row) * ldk + kb + kc * 8;
      gload16(Ah + ga, sAh + lb);
      gload16(Al + ga, sAl + lb);
      gload16(Bh + gb, sBh + lb);
      gload16(Bl + gb, sBl + lb);
    }
    __syncthreads();
#pragma unroll
    for (int kk = 0; kk < 2; kk++) {
      const int kc = kk * 4 + quad;
      f16x8 a_h[4], a_l[4], b_h[2], b_l[2];
#pragma unroll
      for (int t = 0; t < 4; t++) {
        int ar = wn + t * 16 + rl;
        a_h[t] = *(const f16x8*)&sAh[(kc * 128 + ar) * 8];
        a_l[t] = *(const f16x8*)&sAl[(kc * 128 + ar) * 8];
      }
#pragma unroll
      for (int t = 0; t < 2; t++) {
        int bp = wp + t * 16 + rl;
        b_h[t] = *(const f16x8*)&sBh[(kc * 128 + bp) * 8];
        b_l[t] = *(const f16x8*)&sBl[(kc * 128 + bp) * 8];
      }
#pragma unroll
      for (int mt = 0; mt < 4; mt++)
#pragma unroll
        for (int nt = 0; nt < 2; nt++)
          acc0[mt][nt] = __builtin_amdgcn_mfma_f32_16x16x32_f16(a_h[mt], b_h[nt], acc0[mt][nt], 0, 0, 0);
#pragma unroll
      for (int mt = 0; mt < 4; mt++)
#pragma unroll
        for (int nt = 0; nt < 2; nt++)
          acc1[mt][nt] = __builtin_amdgcn_mfma_f32_16x16x32_f16(a_l[mt], b_h[nt], acc1[mt][nt], 0, 0, 0);
#pragma unroll
      for (int mt = 0; mt < 4; mt++)
#pragma unroll
        for (int nt = 0; nt < 2; nt++)
          acc1[mt][nt] = __builtin_amdgcn_mfma_f32_16x16x32_f16(a_h[mt], b_l[nt], acc1[mt][nt], 0, 0, 0);
    }
  }
}

// ---- main-loop GEMM: part[z] = Cp x DtD (combined fp32) ----
__global__ __launch_bounds__(512, 2) void k_mm(const _Float16* __restrict__ Ch, const _Float16* __restrict__ Cl,
                                               const _Float16* __restrict__ H, const _Float16* __restrict__ Ee,
                                               float* __restrict__ part) {
  f32x4 acc0[4][2], acc1[4][2];
  const int n0 = blockIdx.x * 128, p0 = blockIdx.y * 128;
  mm3_core(Ch, Cl, H, Ee, 2048, n0, p0, blockIdx.z * 1024, 16, acc0, acc1);
  const int lane = threadIdx.x & 63, wave = threadIdx.x >> 6;
  const int quad = lane >> 4, rl = lane & 15;
  const int wn = (wave >> 2) * 64, wp = (wave & 3) * 32;
  float* op = part + (size_t)blockIdx.z * NB * NP;
#pragma unroll
  for (int mt = 0; mt < 4; mt++)
#pragma unroll
    for (int nt = 0; nt < 2; nt++)
#pragma unroll
      for (int r = 0; r < 4; r++) {
        int row = n0 + wn + mt * 16 + quad * 4 + r;
        int col = p0 + wp + nt * 16 + rl;
        op[(size_t)row * NP + col] = acc0[mt][nt][r] + acc1[mt][nt][r] * (1.f / 4096.f);
      }
}

// ---- DtD = Dt x Dt (K=1024), emits H = f16(DtD), Ee = f16((DtD-H)*4096) ----
__global__ __launch_bounds__(512, 2) void k_dtd(const _Float16* __restrict__ Dth, const _Float16* __restrict__ Dtl,
                                                _Float16* __restrict__ H, _Float16* __restrict__ Ee) {
  f32x4 acc0[4][2], acc1[4][2];
  const int n0 = blockIdx.x * 128, p0 = blockIdx.y * 128;
  mm3_core(Dth, Dtl, Dth, Dtl, 1024, n0, p0, 0, 16, acc0, acc1);
  const int lane = threadIdx.x & 63, wave = threadIdx.x >> 6;
  const int quad = lane >> 4, rl = lane & 15;
  const int wn = (wave >> 2) * 64, wp = (wave & 3) * 32;
#pragma unroll
  for (int mt = 0; mt < 4; mt++)
#pragma unroll
    for (int nt = 0; nt < 2; nt++)
#pragma unroll
      for (int r = 0; r < 4; r++) {
        int row = n0 + wn + mt * 16 + quad * 4 + r;
        int col = p0 + wp + nt * 16 + rl;
        float v = acc0[mt][nt][r] + acc1[mt][nt][r] * (1.f / 4096.f);
        _Float16 h = (_Float16)v;
        H[(size_t)row * NP + col] = h;
        Ee[(size_t)row * NP + col] = (_Float16)((v - (float)h) * 4096.f);
      }
}

// ---- G = D x D (K=2048) fp32 + ||G||_F^2 ----
__global__ __launch_bounds__(512, 2) void k_g(const _Float16* __restrict__ Dh, const _Float16* __restrict__ Dl,
                                              float* __restrict__ G, float* __restrict__ ss0) {
  f32x4 acc0[4][2], acc1[4][2];
  const int n0 = blockIdx.x * 128, p0 = blockIdx.y * 128;
  mm3_core(Dh, Dl, Dh, Dl, 2048, n0, p0, 0, 32, acc0, acc1);
  const int tid = threadIdx.x, lane = tid & 63, wave = tid >> 6;
  const int quad = lane >> 4, rl = lane & 15;
  const int wn = (wave >> 2) * 64, wp = (wave & 3) * 32;
  float ssl = 0.f;
#pragma unroll
  for (int mt = 0; mt < 4; mt++)
#pragma unroll
    for (int nt = 0; nt < 2; nt++)
#pragma unroll
      for (int r = 0; r < 4; r++) {
        int row = n0 + wn + mt * 16 + quad * 4 + r;
        int col = p0 + wp + nt * 16 + rl;
        float v = acc0[mt][nt][r] + acc1[mt][nt][r] * (1.f / 4096.f);
        G[(size_t)row * 1024 + col] = v;
        ssl = fmaf(v, v, ssl);
      }
  __shared__ float red[512];
  red[tid] = ssl; __syncthreads();
  for (int off = 256; off > 0; off >>= 1) {
    if (tid < off) red[tid] += red[tid + off];
    __syncthreads();
  }
  if (tid == 0) atomicAdd(ss0, red[0]);
}

// ---- DtY[n][p] = Yt x Dt (K=1024) fp32 ----
__global__ __launch_bounds__(512, 2) void k_dty(const _Float16* __restrict__ Yth, const _Float16* __restrict__ Ytl,
                                                const _Float16* __restrict__ Dth, const _Float16* __restrict__ Dtl,
                                                float* __restrict__ DtY_) {
  f32x4 acc0[4][2], acc1[4][2];
  const int n0 = blockIdx.x * 128, p0 = blockIdx.y * 128;
  mm3_core(Yth, Ytl, Dth, Dtl, 1024, n0, p0, 0, 16, acc0, acc1);
  const int lane = threadIdx.x & 63, wave = threadIdx.x >> 6;
  const int quad = lane >> 4, rl = lane & 15;
  const int wn = (wave >> 2) * 64, wp = (wave & 3) * 32;
#pragma unroll
  for (int mt = 0; mt < 4; mt++)
#pragma unroll
    for (int nt = 0; nt < 2; nt++)
#pragma unroll
      for (int r = 0; r < 4; r++) {
        int row = n0 + wn + mt * 16 + quad * 4 + r;
        int col = p0 + wp + nt * 16 + rl;
        DtY_[(size_t)row * NP + col] = acc0[mt][nt][r] + acc1[mt][nt][r] * (1.f / 4096.f);
      }
}

// ---- single-pass f16 squaring (direction only): out = (Mh@Mh)*invfac/ssPrev + frob ----
__global__ __launch_bounds__(512, 2) void k_sqf(const _Float16* __restrict__ Mh, const float* __restrict__ ssPrev,
                                                float* __restrict__ Mout, float* __restrict__ ssNext, float invfac) {
  __shared__ __align__(16) _Float16 sA[8192], sB[8192];
  const int tid = threadIdx.x;
  const int lane = tid & 63, wave = tid >> 6;
  const int quad = lane >> 4, rl = lane & 15;
  const int wn = (wave >> 2) * 64, wp = (wave & 3) * 32;
  const int n0 = blockIdx.x * 128, p0 = blockIdx.y * 128;
  f32x4 acc[4][2];
#pragma unroll
  for (int i = 0; i < 4; i++)
#pragma unroll
    for (int j = 0; j < 2; j++) acc[i][j] = (f32x4)0.0f;

  for (int s = 0; s < 16; s++) {
    const int kb = s * 64;
    if (s) __syncthreads();
#pragma unroll
    for (int i = 0; i < 2; i++) {
      int slot = i * 512 + wave * 64 + lane;
      int kc = slot >> 7, row = slot & 127;
      int lb = (i * 512 + wave * 64) * 8;
      gload16(Mh + (size_t)(n0 + row) * 1024 + kb + kc * 8, sA + lb);
      gload16(Mh + (size_t)(p0 + row) * 1024 + kb + kc * 8, sB + lb);
    }
    __syncthreads();
#pragma unroll
    for (int kk = 0; kk < 2; kk++) {
      const int kc = kk * 4 + quad;
      f16x8 a[4], b[2];
#pragma unroll
      for (int t = 0; t < 4; t++) a[t] = *(const f16x8*)&sA[(kc * 128 + wn + t * 16 + rl) * 8];
#pragma unroll
      for (int t = 0; t < 2; t++) b[t] = *(const f16x8*)&sB[(kc * 128 + wp + t * 16 + rl) * 8];
#pragma unroll
      for (int mt = 0; mt < 4; mt++)
#pragma unroll
        for (int nt = 0; nt < 2; nt++)
          acc[mt][nt] = __builtin_amdgcn_mfma_f32_16x16x32_f16(a[mt], b[nt], acc[mt][nt], 0, 0, 0);
    }
  }
  const float inv = invfac / ssPrev[0];
  float ssl = 0.f;
#pragma unroll
  for (int mt = 0; mt < 4; mt++)
#pragma unroll
    for (int nt = 0; nt < 2; nt++)
#pragma unroll
      for (int r = 0; r < 4; r++) {
        int row = n0 + wn + mt * 16 + quad * 4 + r;
        int col = p0 + wp + nt * 16 + rl;
        float v = acc[mt][nt][r] * inv;
        Mout[(size_t)row * 1024 + col] = v;
        ssl = fmaf(v, v, ssl);
      }
  __shared__ float red[512];
  red[tid] = ssl; __syncthreads();
  for (int off = 256; off > 0; off >>= 1) {
    if (tid < off) red[tid] += red[tid + off];
    __syncthreads();
  }
  if (tid == 0) atomicAdd(ssNext, red[0]);
}

// ---- epilogue: grad/soft-threshold/momentum + f16 pair re-split ----
__global__ __launch_bounds__(256) void k_epi(const float* __restrict__ part,
    const float* __restrict__ DtY_, const float* __restrict__ CcIn,
    const _Float16* __restrict__ ChIn, const _Float16* __restrict__ ClIn,
    const float* __restrict__ Lptr, const float* __restrict__ thrM, float tc,
    float* __restrict__ CcOut, _Float16* __restrict__ ChOut, _Float16* __restrict__ ClOut) {
  const size_t g = ((size_t)blockIdx.x * 256 + threadIdx.x) * 4;
  const float Lv = Lptr[0];
  float p0[4], p1[4], dy[4], cc[4], th[4];
  *(float4*)p0 = *(const float4*)(part + g);
  *(float4*)p1 = *(const float4*)(part + (size_t)NB * NP + g);
  *(float4*)dy = *(const float4*)(DtY_ + g);
  *(float4*)cc = *(const float4*)(CcIn + g);
  f16x4 chv = *(const f16x4*)(ChIn + g);
  f16x4 clv = *(const f16x4*)(ClIn + g);
  if (thrM) { *(float4*)th = *(const float4*)(thrM + g); }
  float cn[4];
  f16x4 ho, lo;
#pragma unroll
  for (int j = 0; j < 4; j++) {
    float grad = (p0[j] + p1[j]) - dy[j];
    float cp = (float)chv[j] + (float)clv[j] * (1.f / 4096.f);
    float z = cp - Lv * grad;
    float t2 = thrM ? th[j] : Lv * LAM0;
    float az = fabsf(z) - t2;
    float v = az > 0.f ? copysignf(az, z) : 0.f;
    cn[j] = v;
    float cpn = fmaf(tc, v - cc[j], v);
    _Float16 h = (_Float16)cpn;
    ho[j] = h;
    lo[j] = (_Float16)((cpn - (float)h) * 4096.f);
  }
  *(float4*)(CcOut + g) = *(float4*)cn;
  *(f16x4*)(ChOut + g) = ho;
  *(f16x4*)(ClOut + g) = lo;
}

// ---- fp32 -> f16 (h, l*4096) split ----
__global__ __launch_bounds__(256) void k_split(const float* __restrict__ src, _Float16* __restrict__ H,
                                               _Float16* __restrict__ L, int n4) {
  int g = blockIdx.x * 256 + threadIdx.x;
  if (g < n4) {
    float4 v = ((const float4*)src)[g];
    float vv[4] = {v.x, v.y, v.z, v.w};
    f16x4 h, l;
#pragma unroll
    for (int j = 0; j < 4; j++) {
      _Float16 hh = (_Float16)vv[j];
      h[j] = hh;
      l[j] = (_Float16)((vv[j] - (float)hh) * 4096.f);
    }
    ((f16x4*)H)[g] = h;
    ((f16x4*)L)[g] = l;
  }
}

// ---- fp32 -> f16 with scale ----
__global__ __launch_bounds__(256) void k_h16(const float* __restrict__ src, _Float16* __restrict__ dst,
                                             int n4, float scale) {
  int g = blockIdx.x * 256 + threadIdx.x;
  if (g < n4) {
    float4 v = ((const float4*)src)[g];
    f16x4 h;
    h[0] = (_Float16)(v.x * scale); h[1] = (_Float16)(v.y * scale);
    h[2] = (_Float16)(v.z * scale); h[3] = (_Float16)(v.w * scale);
    ((f16x4*)dst)[g] = h;
  }
}

// ---- fp32 transpose: src[R][C] -> dst[C][R], 64x64 tiles ----
__global__ __launch_bounds__(256) void k_tr(const float* __restrict__ src, float* __restrict__ dst,
                                            int R, int C) {
  __shared__ float T[64][65];
  const int tid = threadIdx.x;
  const int c0 = blockIdx.x * 64, r0 = blockIdx.y * 64;
  const int cx = tid & 15, ry = tid >> 4;
#pragma unroll
  for (int ii = 0; ii < 4; ii++) {
    int r = ry + ii * 16;
    float4 v = *(const float4*)(src + (size_t)(r0 + r) * C + c0 + cx * 4);
    T[cx * 4 + 0][r] = v.x; T[cx * 4 + 1][r] = v.y;
    T[cx * 4 + 2][r] = v.z; T[cx * 4 + 3][r] = v.w;
  }
  __syncthreads();
#pragma unroll
  for (int ii = 0; ii < 4; ii++) {
    int c = ry + ii * 16;
    float4 v = make_float4(T[c][cx * 4], T[c][cx * 4 + 1], T[c][cx * 4 + 2], T[c][cx * 4 + 3]);
    *(float4*)(dst + (size_t)(c0 + c) * R + r0 + cx * 4) = v;
  }
}

// ---- Y[b][t][j] -> Yt[b*64+j][t] ----
__global__ __launch_bounds__(256) void k_trY(const float* __restrict__ Y, float* __restrict__ Yt) {
  __shared__ float T[64][65];
  const int tid = threadIdx.x;
  const int t0 = blockIdx.x * 64, b = blockIdx.y;
  const int cx = tid & 15, ry = tid >> 4;
#pragma unroll
  for (int ii = 0; ii < 4; ii++) {
    int r = ry + ii * 16;  // t-offset
    float4 v = *(const float4*)(Y + ((size_t)b * T_DIM + t0 + r) * 64 + cx * 4);
    T[cx * 4 + 0][r] = v.x; T[cx * 4 + 1][r] = v.y;
    T[cx * 4 + 2][r] = v.z; T[cx * 4 + 3][r] = v.w;
  }
  __syncthreads();
#pragma unroll
  for (int ii = 0; ii < 4; ii++) {
    int j = ry + ii * 16;
    float4 v = make_float4(T[j][cx * 4], T[j][cx * 4 + 1], T[j][cx * 4 + 2], T[j][cx * 4 + 3]);
    *(float4*)(Yt + ((size_t)b * 64 + j) * T_DIM + t0 + cx * 4) = v;
  }
}

__global__ void k_initx(float* __restrict__ X) {
  int g = blockIdx.x * 256 + threadIdx.x;
  if (g < 4096) {
    unsigned h = (unsigned)g * 2654435761u;
    h ^= h >> 16; h *= 2246822519u; h ^= h >> 13;
    X[g] = ((float)(h & 0xffffff) / 16777216.0f) - 0.5f;
  }
}

// ---- power step: 256 blocks x 4 rows, 4 cols, lazy normalization ----
__global__ __launch_bounds__(256) void k_matvec(const float* __restrict__ M, const float* __restrict__ Xin,
                                                float* __restrict__ Xout, const float* __restrict__ prevNorm,
                                                float* __restrict__ outNorm) {
  const int tid = threadIdx.x, lane = tid & 63, w = tid >> 6;
  const int row = blockIdx.x * 4 + w;
  const float* Mr = M + (size_t)row * 1024;
  float s[4] = {0.f, 0.f, 0.f, 0.f};
  for (int j = 0; j < 16; j++) {
    int k = j * 64 + lane;
    float m = Mr[k];
    float4 x = *(const float4*)(Xin + k * 4);
    s[0] = fmaf(m, x.x, s[0]); s[1] = fmaf(m, x.y, s[1]);
    s[2] = fmaf(m, x.z, s[2]); s[3] = fmaf(m, x.w, s[3]);
  }
#pragma unroll
  for (int off = 32; off > 0; off >>= 1)
#pragma unroll
    for (int c = 0; c < 4; c++) s[c] += __shfl_down(s[c], off, 64);
  __shared__ float red[16];
  if (lane == 0) {
#pragma unroll
    for (int c = 0; c < 4; c++) {
      float sc = prevNorm ? rsqrtf(prevNorm[c]) : 1.0f;
      float o = s[c] * sc;
      Xout[row * 4 + c] = o;
      red[w * 4 + c] = o * o;
    }
  }
  __syncthreads();
  if (tid < 4) atomicAdd(&outNorm[tid], red[tid] + red[4 + tid] + red[8 + tid] + red[12 + tid]);
}

// ---- Rayleigh quotient vs original G (scale-invariant) ----
__global__ __launch_bounds__(256) void k_rq(const float* __restrict__ G, const float* __restrict__ X,
                                            float* __restrict__ num, float* __restrict__ den) {
  const int tid = threadIdx.x, lane = tid & 63, w = tid >> 6;
  const int row = blockIdx.x * 4 + w;
  const float* Gr = G + (size_t)row * 1024;
  float s[4] = {0.f, 0.f, 0.f, 0.f};
  for (int j = 0; j < 16; j++) {
    int k = j * 64 + lane;
    float m = Gr[k];
    float4 x = *(const float4*)(X + k * 4);
    s[0] = fmaf(m, x.x, s[0]); s[1] = fmaf(m, x.y, s[1]);
    s[2] = fmaf(m, x.z, s[2]); s[3] = fmaf(m, x.w, s[3]);
  }
#pragma unroll
  for (int off = 32; off > 0; off >>= 1)
#pragma unroll
    for (int c = 0; c < 4; c++) s[c] += __shfl_down(s[c], off, 64);
  __shared__ float rn[16], rd[16];
  if (lane == 0) {
    float4 v = *(const float4*)(X + row * 4);
    float vv[4] = {v.x, v.y, v.z, v.w};
#pragma unroll
    for (int c = 0; c < 4; c++) { rn[w * 4 + c] = vv[c] * s[c]; rd[w * 4 + c] = vv[c] * vv[c]; }
  }
  __syncthreads();
  if (tid < 4) {
    atomicAdd(&num[tid], rn[tid] + rn[4 + tid] + rn[8 + tid] + rn[12 + tid]);
    atomicAdd(&den[tid], rd[tid] + rd[4 + tid] + rd[8 + tid] + rd[12 + tid]);
  }
}

__global__ void k_finL(const float* __restrict__ num, const float* __restrict__ den, float* __restrict__ Lout) {
  if (threadIdx.x == 0 && blockIdx.x == 0) {
    float best = 0.f;
    for (int c = 0; c < 4; c++) { float r = num[c] / den[c]; best = fmaxf(best, r); }
    Lout[0] = 1.0f / best;
  }
}

// rowss[n] = sum_p (1/(|Cc[n][p]|+eps))^2
__global__ __launch_bounds__(256) void k_rowss(const float* __restrict__ Cc, float* __restrict__ rowss) {
  const int n = blockIdx.x, tid = threadIdx.x;
  const float4* row = (const float4*)(Cc + (size_t)n * NP);
  float s = 0.f;
  for (int i = tid; i < 512; i += 256) {
    float4 v = row[i];
    float r0 = 1.f / (fabsf(v.x) + EPS_W), r1 = 1.f / (fabsf(v.y) + EPS_W);
    float r2 = 1.f / (fabsf(v.z) + EPS_W), r3 = 1.f / (fabsf(v.w) + EPS_W);
    s += r0 * r0 + r1 * r1 + r2 * r2 + r3 * r3;
  }
  __shared__ float red[256];
  red[tid] = s; __syncthreads();
  for (int off = 128; off > 0; off >>= 1) {
    if (tid < off) red[tid] += red[tid + off];
    __syncthreads();
  }
  if (tid == 0) rowss[n] = red[0];
}

__global__ __launch_bounds__(256) void k_thrmat(const float* __restrict__ Cc, const float* __restrict__ rowss,
                                                const float* __restrict__ Lptr, float* __restrict__ thrMat) {
  const size_t g = (size_t)blockIdx.x * 256 + threadIdx.x;
  const int n = (int)(g >> 11);
  float r = 1.0f / (fabsf(Cc[g]) + EPS_W);
  thrMat[g] = Lptr[0] * LAM0 * (float)NP * r * rsqrtf(rowss[n]);
}

// out[b][p][j] = Cc[n=b*64+j][p]
__global__ __launch_bounds__(256) void k_out(const float* __restrict__ Cc, float* __restrict__ out) {
  __shared__ float T[64][65];
  const int tid = threadIdx.x;
  const int p0 = blockIdx.x * 64, nt = blockIdx.y;
  const int pr = tid & 15, nr = tid >> 4;
#pragma unroll
  for (int ii = 0; ii < 4; ii++) {
    int n_l = nr + ii * 16;
    float4 v = *(const float4*)(Cc + ((size_t)nt * 64 + n_l) * NP + p0 + pr * 4);
    T[pr * 4 + 0][n_l] = v.x; T[pr * 4 + 1][n_l] = v.y;
    T[pr * 4 + 2][n_l] = v.z; T[pr * 4 + 3][n_l] = v.w;
  }
  __syncthreads();
#pragma unroll
  for (int ii = 0; ii < 4; ii++) {
    int p_l = nr + ii * 16;
    float4 v = make_float4(T[p_l][pr * 4], T[p_l][pr * 4 + 1], T[p_l][pr * 4 + 2], T[p_l][pr * 4 + 3]);
    *(float4*)(out + (size_t)nt * (NP * 64) + (size_t)(p0 + p_l) * 64 + pr * 4) = v;
  }
}

#define MBf(x) ((size_t)(x) * 262144)   // MB -> float count

extern "C" void kernel_launch(void* const* d_in, const int* in_sizes, int n_in,
                              void* d_out, int out_size, void* d_ws, size_t ws_size,
                              hipStream_t stream) {
  const float* Y = (const float*)d_in[0];   // [16,1024,64]
  const float* D = (const float*)d_in[1];   // [1024,2048]
  float* out = (float*)d_out;
  float* ws = (float*)d_ws;

  float*    part = ws;                               // 16 MB (2 z-slices)
  float*    Dt   = ws;                               // 8 MB (aliased, pre-loop only)
  float*    Yt   = ws + MBf(8);                      // 4 MB (aliased, pre-loop only)
  _Float16* H    = (_Float16*)(ws + MBf(16));        // 8 MB
  _Float16* Ee   = (_Float16*)(ws + MBf(24));        // 8 MB
  float*    DtY  = ws + MBf(32);                     // 8 MB
  float*    Cc0  = ws + MBf(40);
  float*    Cc1  = ws + MBf(48);
  _Float16* Ch0  = (_Float16*)(ws + MBf(56));        // 4 MB
  _Float16* Cl0  = (_Float16*)(ws + MBf(60));
  _Float16* Ch1  = (_Float16*)(ws + MBf(64));
  _Float16* Cl1  = (_Float16*)(ws + MBf(68));
  float*    thrM = ws + MBf(72);                     // 8 MB
  float*    G    = ws + MBf(80);                     // 4 MB
  float*    S0   = ws + MBf(84);
  float*    S1   = ws + MBf(88);
  _Float16* Mh   = (_Float16*)(ws + MBf(92));        // 2 MB
  _Float16* Dh   = (_Float16*)(ws + MBf(94));        // 4 MB
  _Float16* Dl   = (_Float16*)(ws + MBf(98));
  _Float16* Dth  = (_Float16*)(ws + MBf(102));
  _Float16* Dtl  = (_Float16*)(ws + MBf(106));
  _Float16* Yth  = (_Float16*)(ws + MBf(110));       // 2 MB
  _Float16* Ytl  = (_Float16*)(ws + MBf(112));
  float*    XA   = ws + MBf(114);
  float*    XB   = XA + 4096;
  float*    scal = XB + 4096;
  float*    ssv   = scal;                // [8]
  float*    norms = scal + 8;            // [NPI*4]
  float*    num   = scal + 8 + NPI * 4;  // [4]
  float*    den   = num + 4;             // [4]
  float*    Lp    = den + 4;             // [1..4]
  float*    rowss = Lp + 4;              // [1024]

  float*    CcB[2] = {Cc0, Cc1};
  _Float16* ChB[2] = {Ch0, Ch1};
  _Float16* ClB[2] = {Cl0, Cl1};

  hipMemsetAsync(Cc0, 0, (size_t)NB * NP * sizeof(float), stream);
  hipMemsetAsync(Ch0, 0, (size_t)2 * NB * NP * sizeof(_Float16), stream);  // Ch0+Cl0 contiguous
  hipMemsetAsync(scal, 0, (8 + NPI * 4 + 16) * sizeof(float), stream);

  k_initx<<<16, 256, 0, stream>>>(XA);
  // transposes + splits
  k_tr <<<dim3(32, 16), 256, 0, stream>>>(D, Dt, 1024, 2048);
  k_trY<<<dim3(16, 16), 256, 0, stream>>>(Y, Yt);
  k_split<<<2048, 256, 0, stream>>>(D,  Dh,  Dl,  (T_DIM * NP) / 4);
  k_split<<<2048, 256, 0, stream>>>(Dt, Dth, Dtl, (T_DIM * NP) / 4);
  k_split<<<1024, 256, 0, stream>>>(Yt, Yth, Ytl, (NB * T_DIM) / 4);
  // Gram + operator + data-term
  k_g  <<<dim3(8, 8),   512, 0, stream>>>(Dh, Dl, G, ssv);
  k_dtd<<<dim3(16, 16), 512, 0, stream>>>(Dth, Dtl, H, Ee);
  k_dty<<<dim3(8, 16),  512, 0, stream>>>(Yth, Ytl, Dth, Dtl, DtY);
  // spectral norm: 7 f16 squarings (G^128) + 8 power steps + Rayleigh on G
  k_h16<<<1024, 256, 0, stream>>>(G, Mh, (1024 * 1024) / 4, 1.0f / 64.0f);
  float* SB[2] = {S0, S1};
  for (int l = 0; l < NSQ; l++) {
    float invfac = (l == 0) ? 4096.0f : (1.0f / 16777216.0f);
    k_sqf<<<dim3(8, 8), 512, 0, stream>>>(Mh, ssv + l, SB[l & 1], ssv + l + 1, invfac);
    if (l + 1 < NSQ)
      k_h16<<<1024, 256, 0, stream>>>(SB[l & 1], Mh, (1024 * 1024) / 4, 4096.0f);
  }
  float* Mfin = SB[(NSQ - 1) & 1];
  for (int i = 0; i < NPI; i++) {
    const float* xin = (i & 1) ? XB : XA;
    float* xout = (i & 1) ? XA : XB;
    k_matvec<<<256, 256, 0, stream>>>(Mfin, xin, xout,
                                      i ? norms + (i - 1) * 4 : nullptr, norms + i * 4);
  }
  k_rq  <<<256, 256, 0, stream>>>(G, XA, num, den);
  k_finL<<<1, 64, 0, stream>>>(num, den, Lp);

  // deterministic momentum sequence (done-flag can never trigger: ||dC||_F >> 1e-6)
  float tcv[2 * NITER];
  {
    float t = 1.0f;
    for (int i = 0; i < 2 * NITER; i++) {
      float tn = 0.5f * (1.0f + sqrtf(1.0f + 4.0f * t * t));
      tcv[i] = (t - 1.0f) / tn;
      t = tn;
    }
  }

  for (int i = 0; i < 2 * NITER; i++) {
    int a = i & 1, b = (i + 1) & 1;
    if (i == NITER) {
      k_rowss <<<1024, 256, 0, stream>>>(CcB[a], rowss);
      k_thrmat<<<(NB * NP) / 256, 256, 0, stream>>>(CcB[a], rowss, Lp, thrM);
    }
    const float* thr = (i < NITER) ? nullptr : thrM;
    k_mm <<<dim3(8, 16, 2), 512, 0, stream>>>(ChB[a], ClB[a], H, Ee, part);
    k_epi<<<(NB * NP) / 1024, 256, 0, stream>>>(part, DtY, CcB[a], ChB[a], ClB[a], Lp, thr,
                                                tcv[i], CcB[b], ChB[b], ClB[b]);
  }
  k_out<<<dim3(32, 16), 256, 0, stream>>>(CcB[0], out);
}

// Round 5
// 3816.016 us; speedup vs baseline: 3.6300x; 1.0640x over previous
//
#include <hip/hip_runtime.h>
#include <math.h>

#define T_DIM 1024
#define NP    2048
#define NB    1024
#define NITER 25
#define NSQ   7
#define NPI   8
#define LAM0  0.1f
#define EPS_W 1e-10f

typedef float    f32x4 __attribute__((ext_vector_type(4)));
typedef _Float16 f16x8 __attribute__((ext_vector_type(8)));
typedef _Float16 f16x4 __attribute__((ext_vector_type(4)));

__device__ __forceinline__ void gload16(const void* g, void* l) {
  __builtin_amdgcn_global_load_lds((const __attribute__((address_space(1))) unsigned int*)g,
                                   (__attribute__((address_space(3))) unsigned int*)l, 16, 0, 0);
}

// =====================================================================
// Dual-accumulator 3-pass split-f16 GEMM core.
// acc0 = Ah.Bh ; acc1 = Al.Bh + Ah.Bl (scale 2^12); result acc0 + acc1/4096.
// 512 threads = 8 waves, block tile 128(n) x 128(p), wave tile 64x32.
// =====================================================================
__device__ __forceinline__ void mm3_core(
    const _Float16* __restrict__ Ah, const _Float16* __restrict__ Al,
    const _Float16* __restrict__ Bh, const _Float16* __restrict__ Bl,
    int ldk, int n0, int p0, int kb0, int nsteps,
    f32x4 acc0[4][2], f32x4 acc1[4][2])
{
  __shared__ __align__(16) _Float16 sAh[8192], sAl[8192], sBh[8192], sBl[8192];
  const int tid = threadIdx.x;
  const int lane = tid & 63, wave = tid >> 6;
  const int quad = lane >> 4, rl = lane & 15;
#pragma unroll
  for (int i = 0; i < 4; i++)
#pragma unroll
    for (int j = 0; j < 2; j++) { acc0[i][j] = (f32x4)0.0f; acc1[i][j] = (f32x4)0.0f; }
  const int wn = (wave >> 2) * 64, wp = (wave & 3) * 32;

  for (int s = 0; s < nsteps; s++) {
    const int kb = kb0 + s * 64;
    if (s) __syncthreads();
#pragma unroll
    for (int i = 0; i < 2; i++) {
      int slot = i * 512 + wave * 64 + lane;
      int kc = slot >> 7, row = slot & 127;
      int lb = (i * 512 + wave * 64) * 8;     // wave-uniform LDS base (elements)
      size_t ga = (size_t)(n0 + row) * ldk + kb + kc * 8;
      size_t gb = (size_t)(p0 + row) * ldk + kb + kc * 8;
      gload16(Ah + ga, sAh + lb);
      gload16(Al + ga, sAl + lb);
      gload16(Bh + gb, sBh + lb);
      gload16(Bl + gb, sBl + lb);
    }
    __syncthreads();
#pragma unroll
    for (int kk = 0; kk < 2; kk++) {
      const int kc = kk * 4 + quad;
      f16x8 a_h[4], a_l[4], b_h[2], b_l[2];
#pragma unroll
      for (int t = 0; t < 4; t++) {
        int ar = wn + t * 16 + rl;
        a_h[t] = *(const f16x8*)&sAh[(kc * 128 + ar) * 8];
        a_l[t] = *(const f16x8*)&sAl[(kc * 128 + ar) * 8];
      }
#pragma unroll
      for (int t = 0; t < 2; t++) {
        int bp = wp + t * 16 + rl;
        b_h[t] = *(const f16x8*)&sBh[(kc * 128 + bp) * 8];
        b_l[t] = *(const f16x8*)&sBl[(kc * 128 + bp) * 8];
      }
#pragma unroll
      for (int mt = 0; mt < 4; mt++)
#pragma unroll
        for (int nt = 0; nt < 2; nt++)
          acc0[mt][nt] = __builtin_amdgcn_mfma_f32_16x16x32_f16(a_h[mt], b_h[nt], acc0[mt][nt], 0, 0, 0);
#pragma unroll
      for (int mt = 0; mt < 4; mt++)
#pragma unroll
        for (int nt = 0; nt < 2; nt++)
          acc1[mt][nt] = __builtin_amdgcn_mfma_f32_16x16x32_f16(a_l[mt], b_h[nt], acc1[mt][nt], 0, 0, 0);
#pragma unroll
      for (int mt = 0; mt < 4; mt++)
#pragma unroll
        for (int nt = 0; nt < 2; nt++)
          acc1[mt][nt] = __builtin_amdgcn_mfma_f32_16x16x32_f16(a_h[mt], b_l[nt], acc1[mt][nt], 0, 0, 0);
    }
  }
}

// ---- main-loop GEMM: part[z] = Cp x DtD, splitK=4, XCD-swizzled 1-D grid ----
// b%8 presumed round-robin XCD: tie XCD to p-pair so each XCD streams only
// 2 p-tiles of H/Ee instead of all 16 MB.
__global__ __launch_bounds__(512, 4) void k_mm(const _Float16* __restrict__ Ch, const _Float16* __restrict__ Cl,
                                               const _Float16* __restrict__ H, const _Float16* __restrict__ Ee,
                                               float* __restrict__ part) {
  const int b = blockIdx.x;
  const int xcd = b & 7, q = b >> 3;
  const int pt = xcd * 2 + (q & 1);   // p tile 0..15
  const int ny = (q >> 1) & 7;        // n tile 0..7
  const int z  = q >> 4;              // K slice 0..3
  f32x4 acc0[4][2], acc1[4][2];
  const int n0 = ny * 128, p0 = pt * 128;
  mm3_core(Ch, Cl, H, Ee, 2048, n0, p0, z * 512, 8, acc0, acc1);
  const int lane = threadIdx.x & 63, wave = threadIdx.x >> 6;
  const int quad = lane >> 4, rl = lane & 15;
  const int wn = (wave >> 2) * 64, wp = (wave & 3) * 32;
  float* op = part + (size_t)z * NB * NP;
#pragma unroll
  for (int mt = 0; mt < 4; mt++)
#pragma unroll
    for (int nt = 0; nt < 2; nt++)
#pragma unroll
      for (int r = 0; r < 4; r++) {
        int row = n0 + wn + mt * 16 + quad * 4 + r;
        int col = p0 + wp + nt * 16 + rl;
        op[(size_t)row * NP + col] = acc0[mt][nt][r] + acc1[mt][nt][r] * (1.f / 4096.f);
      }
}

// ---- DtD = Dt x Dt (K=1024), emits H = f16(DtD), Ee = f16((DtD-H)*4096) ----
__global__ __launch_bounds__(512, 2) void k_dtd(const _Float16* __restrict__ Dth, const _Float16* __restrict__ Dtl,
                                                _Float16* __restrict__ H, _Float16* __restrict__ Ee) {
  f32x4 acc0[4][2], acc1[4][2];
  const int n0 = blockIdx.x * 128, p0 = blockIdx.y * 128;
  mm3_core(Dth, Dtl, Dth, Dtl, 1024, n0, p0, 0, 16, acc0, acc1);
  const int lane = threadIdx.x & 63, wave = threadIdx.x >> 6;
  const int quad = lane >> 4, rl = lane & 15;
  const int wn = (wave >> 2) * 64, wp = (wave & 3) * 32;
#pragma unroll
  for (int mt = 0; mt < 4; mt++)
#pragma unroll
    for (int nt = 0; nt < 2; nt++)
#pragma unroll
      for (int r = 0; r < 4; r++) {
        int row = n0 + wn + mt * 16 + quad * 4 + r;
        int col = p0 + wp + nt * 16 + rl;
        float v = acc0[mt][nt][r] + acc1[mt][nt][r] * (1.f / 4096.f);
        _Float16 h = (_Float16)v;
        H[(size_t)row * NP + col] = h;
        Ee[(size_t)row * NP + col] = (_Float16)((v - (float)h) * 4096.f);
      }
}

// ---- G partials: gpart[z] = D x D over K-slice z (splitK=4) ----
__global__ __launch_bounds__(512, 2) void k_g(const _Float16* __restrict__ Dh, const _Float16* __restrict__ Dl,
                                              float* __restrict__ gpart) {
  f32x4 acc0[4][2], acc1[4][2];
  const int n0 = blockIdx.x * 128, p0 = blockIdx.y * 128;
  mm3_core(Dh, Dl, Dh, Dl, 2048, n0, p0, blockIdx.z * 512, 8, acc0, acc1);
  const int lane = threadIdx.x & 63, wave = threadIdx.x >> 6;
  const int quad = lane >> 4, rl = lane & 15;
  const int wn = (wave >> 2) * 64, wp = (wave & 3) * 32;
  float* op = gpart + (size_t)blockIdx.z * 1024 * 1024;
#pragma unroll
  for (int mt = 0; mt < 4; mt++)
#pragma unroll
    for (int nt = 0; nt < 2; nt++)
#pragma unroll
      for (int r = 0; r < 4; r++) {
        int row = n0 + wn + mt * 16 + quad * 4 + r;
        int col = p0 + wp + nt * 16 + rl;
        op[(size_t)row * 1024 + col] = acc0[mt][nt][r] + acc1[mt][nt][r] * (1.f / 4096.f);
      }
}

// ---- combine G partials + ||G||_F^2 ----
__global__ __launch_bounds__(256) void k_gcomb(const float* __restrict__ gpart, float* __restrict__ G,
                                               float* __restrict__ ss0) {
  const int tid = threadIdx.x;
  const size_t g = ((size_t)blockIdx.x * 256 + tid) * 4;
  float v[4];
  *(float4*)v = *(const float4*)(gpart + g);
#pragma unroll
  for (int z = 1; z < 4; z++) {
    float t[4];
    *(float4*)t = *(const float4*)(gpart + (size_t)z * 1024 * 1024 + g);
#pragma unroll
    for (int j = 0; j < 4; j++) v[j] += t[j];
  }
  *(float4*)(G + g) = *(float4*)v;
  float ssl = 0.f;
#pragma unroll
  for (int j = 0; j < 4; j++) ssl = fmaf(v[j], v[j], ssl);
  __shared__ float red[256];
  red[tid] = ssl; __syncthreads();
  for (int off = 128; off > 0; off >>= 1) {
    if (tid < off) red[tid] += red[tid + off];
    __syncthreads();
  }
  if (tid == 0) atomicAdd(ss0, red[0]);
}

// ---- DtY[n][p] = Yt x Dt (K=1024) fp32 ----
__global__ __launch_bounds__(512, 2) void k_dty(const _Float16* __restrict__ Yth, const _Float16* __restrict__ Ytl,
                                                const _Float16* __restrict__ Dth, const _Float16* __restrict__ Dtl,
                                                float* __restrict__ DtY_) {
  f32x4 acc0[4][2], acc1[4][2];
  const int n0 = blockIdx.x * 128, p0 = blockIdx.y * 128;
  mm3_core(Yth, Ytl, Dth, Dtl, 1024, n0, p0, 0, 16, acc0, acc1);
  const int lane = threadIdx.x & 63, wave = threadIdx.x >> 6;
  const int quad = lane >> 4, rl = lane & 15;
  const int wn = (wave >> 2) * 64, wp = (wave & 3) * 32;
#pragma unroll
  for (int mt = 0; mt < 4; mt++)
#pragma unroll
    for (int nt = 0; nt < 2; nt++)
#pragma unroll
      for (int r = 0; r < 4; r++) {
        int row = n0 + wn + mt * 16 + quad * 4 + r;
        int col = p0 + wp + nt * 16 + rl;
        DtY_[(size_t)row * NP + col] = acc0[mt][nt][r] + acc1[mt][nt][r] * (1.f / 4096.f);
      }
}

// ---- single-pass f16 squaring (direction only) ----
__global__ __launch_bounds__(512, 2) void k_sqf(const _Float16* __restrict__ Mh, const float* __restrict__ ssPrev,
                                                float* __restrict__ Mout, float* __restrict__ ssNext, float invfac) {
  __shared__ __align__(16) _Float16 sA[8192], sB[8192];
  const int tid = threadIdx.x;
  const int lane = tid & 63, wave = tid >> 6;
  const int quad = lane >> 4, rl = lane & 15;
  const int wn = (wave >> 2) * 64, wp = (wave & 3) * 32;
  const int n0 = blockIdx.x * 128, p0 = blockIdx.y * 128;
  f32x4 acc[4][2];
#pragma unroll
  for (int i = 0; i < 4; i++)
#pragma unroll
    for (int j = 0; j < 2; j++) acc[i][j] = (f32x4)0.0f;

  for (int s = 0; s < 16; s++) {
    const int kb = s * 64;
    if (s) __syncthreads();
#pragma unroll
    for (int i = 0; i < 2; i++) {
      int slot = i * 512 + wave * 64 + lane;
      int kc = slot >> 7, row = slot & 127;
      int lb = (i * 512 + wave * 64) * 8;
      gload16(Mh + (size_t)(n0 + row) * 1024 + kb + kc * 8, sA + lb);
      gload16(Mh + (size_t)(p0 + row) * 1024 + kb + kc * 8, sB + lb);
    }
    __syncthreads();
#pragma unroll
    for (int kk = 0; kk < 2; kk++) {
      const int kc = kk * 4 + quad;
      f16x8 a[4], b[2];
#pragma unroll
      for (int t = 0; t < 4; t++) a[t] = *(const f16x8*)&sA[(kc * 128 + wn + t * 16 + rl) * 8];
#pragma unroll
      for (int t = 0; t < 2; t++) b[t] = *(const f16x8*)&sB[(kc * 128 + wp + t * 16 + rl) * 8];
#pragma unroll
      for (int mt = 0; mt < 4; mt++)
#pragma unroll
        for (int nt = 0; nt < 2; nt++)
          acc[mt][nt] = __builtin_amdgcn_mfma_f32_16x16x32_f16(a[mt], b[nt], acc[mt][nt], 0, 0, 0);
    }
  }
  const float inv = invfac / ssPrev[0];
  float ssl = 0.f;
#pragma unroll
  for (int mt = 0; mt < 4; mt++)
#pragma unroll
    for (int nt = 0; nt < 2; nt++)
#pragma unroll
      for (int r = 0; r < 4; r++) {
        int row = n0 + wn + mt * 16 + quad * 4 + r;
        int col = p0 + wp + nt * 16 + rl;
        float v = acc[mt][nt][r] * inv;
        Mout[(size_t)row * 1024 + col] = v;
        ssl = fmaf(v, v, ssl);
      }
  __shared__ float red[512];
  red[tid] = ssl; __syncthreads();
  for (int off = 256; off > 0; off >>= 1) {
    if (tid < off) red[tid] += red[tid + off];
    __syncthreads();
  }
  if (tid == 0) atomicAdd(ssNext, red[0]);
}

// ---- epilogue: combine 4 partials, grad/soft-threshold/momentum, f16 re-split ----
__global__ __launch_bounds__(256) void k_epi(const float* __restrict__ part,
    const float* __restrict__ DtY_, const float* __restrict__ CcIn,
    const _Float16* __restrict__ ChIn, const _Float16* __restrict__ ClIn,
    const float* __restrict__ Lptr, const float* __restrict__ thrM, float tc,
    float* __restrict__ CcOut, _Float16* __restrict__ ChOut, _Float16* __restrict__ ClOut) {
  const size_t g = ((size_t)blockIdx.x * 256 + threadIdx.x) * 4;
  const float Lv = Lptr[0];
  float ps[4], dy[4], cc[4], th[4];
  *(float4*)ps = *(const float4*)(part + g);
#pragma unroll
  for (int z = 1; z < 4; z++) {
    float t[4];
    *(float4*)t = *(const float4*)(part + (size_t)z * NB * NP + g);
#pragma unroll
    for (int j = 0; j < 4; j++) ps[j] += t[j];
  }
  *(float4*)dy = *(const float4*)(DtY_ + g);
  *(float4*)cc = *(const float4*)(CcIn + g);
  f16x4 chv = *(const f16x4*)(ChIn + g);
  f16x4 clv = *(const f16x4*)(ClIn + g);
  if (thrM) { *(float4*)th = *(const float4*)(thrM + g); }
  float cn[4];
  f16x4 ho, lo;
#pragma unroll
  for (int j = 0; j < 4; j++) {
    float grad = ps[j] - dy[j];
    float cp = (float)chv[j] + (float)clv[j] * (1.f / 4096.f);
    float z = cp - Lv * grad;
    float t2 = thrM ? th[j] : Lv * LAM0;
    float az = fabsf(z) - t2;
    float v = az > 0.f ? copysignf(az, z) : 0.f;
    cn[j] = v;
    float cpn = fmaf(tc, v - cc[j], v);
    _Float16 h = (_Float16)cpn;
    ho[j] = h;
    lo[j] = (_Float16)((cpn - (float)h) * 4096.f);
  }
  *(float4*)(CcOut + g) = *(float4*)cn;
  *(f16x4*)(ChOut + g) = ho;
  *(f16x4*)(ClOut + g) = lo;
}

// ---- fp32 -> f16 (h, l*4096) split ----
__global__ __launch_bounds__(256) void k_split(const float* __restrict__ src, _Float16* __restrict__ H,
                                               _Float16* __restrict__ L, int n4) {
  int g = blockIdx.x * 256 + threadIdx.x;
  if (g < n4) {
    float4 v = ((const float4*)src)[g];
    float vv[4] = {v.x, v.y, v.z, v.w};
    f16x4 h, l;
#pragma unroll
    for (int j = 0; j < 4; j++) {
      _Float16 hh = (_Float16)vv[j];
      h[j] = hh;
      l[j] = (_Float16)((vv[j] - (float)hh) * 4096.f);
    }
    ((f16x4*)H)[g] = h;
    ((f16x4*)L)[g] = l;
  }
}

// ---- fp32 -> f16 with scale ----
__global__ __launch_bounds__(256) void k_h16(const float* __restrict__ src, _Float16* __restrict__ dst,
                                             int n4, float scale) {
  int g = blockIdx.x * 256 + threadIdx.x;
  if (g < n4) {
    float4 v = ((const float4*)src)[g];
    f16x4 h;
    h[0] = (_Float16)(v.x * scale); h[1] = (_Float16)(v.y * scale);
    h[2] = (_Float16)(v.z * scale); h[3] = (_Float16)(v.w * scale);
    ((f16x4*)dst)[g] = h;
  }
}

// ---- fp32 transpose: src[R][C] -> dst[C][R], 64x64 tiles ----
__global__ __launch_bounds__(256) void k_tr(const float* __restrict__ src, float* __restrict__ dst,
                                            int R, int C) {
  __shared__ float T[64][65];
  const int tid = threadIdx.x;
  const int c0 = blockIdx.x * 64, r0 = blockIdx.y * 64;
  const int cx = tid & 15, ry = tid >> 4;
#pragma unroll
  for (int ii = 0; ii < 4; ii++) {
    int r = ry + ii * 16;
    float4 v = *(const float4*)(src + (size_t)(r0 + r) * C + c0 + cx * 4);
    T[cx * 4 + 0][r] = v.x; T[cx * 4 + 1][r] = v.y;
    T[cx * 4 + 2][r] = v.z; T[cx * 4 + 3][r] = v.w;
  }
  __syncthreads();
#pragma unroll
  for (int ii = 0; ii < 4; ii++) {
    int c = ry + ii * 16;
    float4 v = make_float4(T[c][cx * 4], T[c][cx * 4 + 1], T[c][cx * 4 + 2], T[c][cx * 4 + 3]);
    *(float4*)(dst + (size_t)(c0 + c) * R + r0 + cx * 4) = v;
  }
}

// ---- Y[b][t][j] -> Yt[b*64+j][t] ----
__global__ __launch_bounds__(256) void k_trY(const float* __restrict__ Y, float* __restrict__ Yt) {
  __shared__ float T[64][65];
  const int tid = threadIdx.x;
  const int t0 = blockIdx.x * 64, b = blockIdx.y;
  const int cx = tid & 15, ry = tid >> 4;
#pragma unroll
  for (int ii = 0; ii < 4; ii++) {
    int r = ry + ii * 16;
    float4 v = *(const float4*)(Y + ((size_t)b * T_DIM + t0 + r) * 64 + cx * 4);
    T[cx * 4 + 0][r] = v.x; T[cx * 4 + 1][r] = v.y;
    T[cx * 4 + 2][r] = v.z; T[cx * 4 + 3][r] = v.w;
  }
  __syncthreads();
#pragma unroll
  for (int ii = 0; ii < 4; ii++) {
    int j = ry + ii * 16;
    float4 v = make_float4(T[j][cx * 4], T[j][cx * 4 + 1], T[j][cx * 4 + 2], T[j][cx * 4 + 3]);
    *(float4*)(Yt + ((size_t)b * 64 + j) * T_DIM + t0 + cx * 4) = v;
  }
}

__global__ void k_initx(float* __restrict__ X) {
  int g = blockIdx.x * 256 + threadIdx.x;
  if (g < 4096) {
    unsigned h = (unsigned)g * 2654435761u;
    h ^= h >> 16; h *= 2246822519u; h ^= h >> 13;
    X[g] = ((float)(h & 0xffffff) / 16777216.0f) - 0.5f;
  }
}

// ---- power step: 256 blocks x 4 rows, 4 cols, lazy normalization ----
__global__ __launch_bounds__(256) void k_matvec(const float* __restrict__ M, const float* __restrict__ Xin,
                                                float* __restrict__ Xout, const float* __restrict__ prevNorm,
                                                float* __restrict__ outNorm) {
  const int tid = threadIdx.x, lane = tid & 63, w = tid >> 6;
  const int row = blockIdx.x * 4 + w;
  const float* Mr = M + (size_t)row * 1024;
  float s[4] = {0.f, 0.f, 0.f, 0.f};
  for (int j = 0; j < 16; j++) {
    int k = j * 64 + lane;
    float m = Mr[k];
    float4 x = *(const float4*)(Xin + k * 4);
    s[0] = fmaf(m, x.x, s[0]); s[1] = fmaf(m, x.y, s[1]);
    s[2] = fmaf(m, x.z, s[2]); s[3] = fmaf(m, x.w, s[3]);
  }
#pragma unroll
  for (int off = 32; off > 0; off >>= 1)
#pragma unroll
    for (int c = 0; c < 4; c++) s[c] += __shfl_down(s[c], off, 64);
  __shared__ float red[16];
  if (lane == 0) {
#pragma unroll
    for (int c = 0; c < 4; c++) {
      float sc = prevNorm ? rsqrtf(prevNorm[c]) : 1.0f;
      float o = s[c] * sc;
      Xout[row * 4 + c] = o;
      red[w * 4 + c] = o * o;
    }
  }
  __syncthreads();
  if (tid < 4) atomicAdd(&outNorm[tid], red[tid] + red[4 + tid] + red[8 + tid] + red[12 + tid]);
}

// ---- Rayleigh quotient vs original G ----
__global__ __launch_bounds__(256) void k_rq(const float* __restrict__ G, const float* __restrict__ X,
                                            float* __restrict__ num, float* __restrict__ den) {
  const int tid = threadIdx.x, lane = tid & 63, w = tid >> 6;
  const int row = blockIdx.x * 4 + w;
  const float* Gr = G + (size_t)row * 1024;
  float s[4] = {0.f, 0.f, 0.f, 0.f};
  for (int j = 0; j < 16; j++) {
    int k = j * 64 + lane;
    float m = Gr[k];
    float4 x = *(const float4*)(X + k * 4);
    s[0] = fmaf(m, x.x, s[0]); s[1] = fmaf(m, x.y, s[1]);
    s[2] = fmaf(m, x.z, s[2]); s[3] = fmaf(m, x.w, s[3]);
  }
#pragma unroll
  for (int off = 32; off > 0; off >>= 1)
#pragma unroll
    for (int c = 0; c < 4; c++) s[c] += __shfl_down(s[c], off, 64);
  __shared__ float rn[16], rd[16];
  if (lane == 0) {
    float4 v = *(const float4*)(X + row * 4);
    float vv[4] = {v.x, v.y, v.z, v.w};
#pragma unroll
    for (int c = 0; c < 4; c++) { rn[w * 4 + c] = vv[c] * s[c]; rd[w * 4 + c] = vv[c] * vv[c]; }
  }
  __syncthreads();
  if (tid < 4) {
    atomicAdd(&num[tid], rn[tid] + rn[4 + tid] + rn[8 + tid] + rn[12 + tid]);
    atomicAdd(&den[tid], rd[tid] + rd[4 + tid] + rd[8 + tid] + rd[12 + tid]);
  }
}

__global__ void k_finL(const float* __restrict__ num, const float* __restrict__ den, float* __restrict__ Lout) {
  if (threadIdx.x == 0 && blockIdx.x == 0) {
    float best = 0.f;
    for (int c = 0; c < 4; c++) { float r = num[c] / den[c]; best = fmaxf(best, r); }
    Lout[0] = 1.0f / best;
  }
}

// rowss[n] = sum_p (1/(|Cc[n][p]|+eps))^2
__global__ __launch_bounds__(256) void k_rowss(const float* __restrict__ Cc, float* __restrict__ rowss) {
  const int n = blockIdx.x, tid = threadIdx.x;
  const float4* row = (const float4*)(Cc + (size_t)n * NP);
  float s = 0.f;
  for (int i = tid; i < 512; i += 256) {
    float4 v = row[i];
    float r0 = 1.f / (fabsf(v.x) + EPS_W), r1 = 1.f / (fabsf(v.y) + EPS_W);
    float r2 = 1.f / (fabsf(v.z) + EPS_W), r3 = 1.f / (fabsf(v.w) + EPS_W);
    s += r0 * r0 + r1 * r1 + r2 * r2 + r3 * r3;
  }
  __shared__ float red[256];
  red[tid] = s; __syncthreads();
  for (int off = 128; off > 0; off >>= 1) {
    if (tid < off) red[tid] += red[tid + off];
    __syncthreads();
  }
  if (tid == 0) rowss[n] = red[0];
}

__global__ __launch_bounds__(256) void k_thrmat(const float* __restrict__ Cc, const float* __restrict__ rowss,
                                                const float* __restrict__ Lptr, float* __restrict__ thrMat) {
  const size_t g = (size_t)blockIdx.x * 256 + threadIdx.x;
  const int n = (int)(g >> 11);
  float r = 1.0f / (fabsf(Cc[g]) + EPS_W);
  thrMat[g] = Lptr[0] * LAM0 * (float)NP * r * rsqrtf(rowss[n]);
}

// out[b][p][j] = Cc[n=b*64+j][p]
__global__ __launch_bounds__(256) void k_out(const float* __restrict__ Cc, float* __restrict__ out) {
  __shared__ float T[64][65];
  const int tid = threadIdx.x;
  const int p0 = blockIdx.x * 64, nt = blockIdx.y;
  const int pr = tid & 15, nr = tid >> 4;
#pragma unroll
  for (int ii = 0; ii < 4; ii++) {
    int n_l = nr + ii * 16;
    float4 v = *(const float4*)(Cc + ((size_t)nt * 64 + n_l) * NP + p0 + pr * 4);
    T[pr * 4 + 0][n_l] = v.x; T[pr * 4 + 1][n_l] = v.y;
    T[pr * 4 + 2][n_l] = v.z; T[pr * 4 + 3][n_l] = v.w;
  }
  __syncthreads();
#pragma unroll
  for (int ii = 0; ii < 4; ii++) {
    int p_l = nr + ii * 16;
    float4 v = make_float4(T[p_l][pr * 4], T[p_l][pr * 4 + 1], T[p_l][pr * 4 + 2], T[p_l][pr * 4 + 3]);
    *(float4*)(out + (size_t)nt * (NP * 64) + (size_t)(p0 + p_l) * 64 + pr * 4) = v;
  }
}

#define MBf(x) ((size_t)(x) * 262144)   // MB -> float count

extern "C" void kernel_launch(void* const* d_in, const int* in_sizes, int n_in,
                              void* d_out, int out_size, void* d_ws, size_t ws_size,
                              hipStream_t stream) {
  const float* Y = (const float*)d_in[0];   // [16,1024,64]
  const float* D = (const float*)d_in[1];   // [1024,2048]
  float* out = (float*)d_out;
  float* ws = (float*)d_ws;

  // ---- In-loop layout (96 MB high-water) ----
  float*    part = ws;                               // 0-32 MB (4 z-slices x 8 MB)
  _Float16* H    = (_Float16*)(ws + MBf(32));        // 32-40 (NP*NP f16 = 8 MB)
  _Float16* Ee   = (_Float16*)(ws + MBf(40));        // 40-48
  float*    DtY  = ws + MBf(48);                     // 48-56 (NB*NP f32 = 8 MB)
  float*    Cc0  = ws + MBf(56);                     // 56-64
  float*    Cc1  = ws + MBf(64);                     // 64-72
  _Float16* Ch0  = (_Float16*)(ws + MBf(72));        // 72-76 (NB*NP f16 = 4 MB!)
  _Float16* Cl0  = (_Float16*)(ws + MBf(76));        // 76-80
  _Float16* Ch1  = (_Float16*)(ws + MBf(80));        // 80-84
  _Float16* Cl1  = (_Float16*)(ws + MBf(84));        // 84-88
  float*    thrM = ws + MBf(88);                     // 88-96
  // ---- Pre-loop-only buffers, overlaid on regions written-before-read in loop ----
  float*    Dt   = ws;                               // 0-8   (in part; dead before k_g)
  float*    Yt   = ws + MBf(8);                      // 8-12  (in part; dead before k_g)
  float*    gpart= ws;                               // 0-16  (in part; dead after k_gcomb)
  float*    G    = ws + MBf(16);                     // 16-20 (in part; dead after k_rq)
  _Float16* Mh   = (_Float16*)(ws + MBf(20));        // 20-22 (in part)
  float*    S0   = ws + MBf(22);                     // 22-26 (in part)
  float*    S1   = ws + MBf(26);                     // 26-30 (in part)
  _Float16* Dh   = (_Float16*)(ws + MBf(64));        // 64-68 (in Cc1; k_epi i=0 writes Cc1)
  _Float16* Dl   = (_Float16*)(ws + MBf(68));        // 68-72 (in Cc1)
  _Float16* Dth  = (_Float16*)(ws + MBf(80));        // 80-84 (in Ch1)
  _Float16* Dtl  = (_Float16*)(ws + MBf(84));        // 84-88 (in Cl1)
  _Float16* Yth  = (_Float16*)(ws + MBf(88));        // 88-90 (in thrM; written i=25)
  _Float16* Ytl  = (_Float16*)(ws + MBf(90));        // 90-92 (in thrM)
  float*    XA   = ws + MBf(96);
  float*    XB   = XA + 4096;
  float*    scal = XB + 4096;
  float*    ssv   = scal;                // [8]
  float*    norms = scal + 8;            // [NPI*4]
  float*    num   = scal + 8 + NPI * 4;  // [4]
  float*    den   = num + 4;             // [4]
  float*    Lp    = den + 4;             // [1..4]
  float*    rowss = Lp + 4;              // [1024]

  float*    CcB[2] = {Cc0, Cc1};
  _Float16* ChB[2] = {Ch0, Ch1};
  _Float16* ClB[2] = {Cl0, Cl1};

  hipMemsetAsync(Cc0, 0, (size_t)NB * NP * sizeof(float), stream);
  hipMemsetAsync(Ch0, 0, (size_t)2 * NB * NP * sizeof(_Float16), stream);  // Ch0+Cl0 contiguous 8 MB
  hipMemsetAsync(scal, 0, (8 + NPI * 4 + 16) * sizeof(float), stream);

  k_initx<<<16, 256, 0, stream>>>(XA);
  // transposes + splits (Dt/Yt consumed here, before k_g overwrites region)
  k_tr <<<dim3(32, 16), 256, 0, stream>>>(D, Dt, 1024, 2048);
  k_trY<<<dim3(16, 16), 256, 0, stream>>>(Y, Yt);
  k_split<<<2048, 256, 0, stream>>>(D,  Dh,  Dl,  (T_DIM * NP) / 4);
  k_split<<<2048, 256, 0, stream>>>(Dt, Dth, Dtl, (T_DIM * NP) / 4);
  k_split<<<1024, 256, 0, stream>>>(Yt, Yth, Ytl, (NB * T_DIM) / 4);
  // Gram (splitK=4) + operator + data-term
  k_g    <<<dim3(8, 8, 4), 512, 0, stream>>>(Dh, Dl, gpart);
  k_gcomb<<<1024, 256, 0, stream>>>(gpart, G, ssv);
  k_dtd  <<<dim3(16, 16), 512, 0, stream>>>(Dth, Dtl, H, Ee);
  k_dty  <<<dim3(8, 16),  512, 0, stream>>>(Yth, Ytl, Dth, Dtl, DtY);
  // spectral norm: 7 f16 squarings (G^128) + 8 power steps + Rayleigh on G
  k_h16<<<1024, 256, 0, stream>>>(G, Mh, (1024 * 1024) / 4, 1.0f / 64.0f);
  float* SB[2] = {S0, S1};
  for (int l = 0; l < NSQ; l++) {
    float invfac = (l == 0) ? 4096.0f : (1.0f / 16777216.0f);
    k_sqf<<<dim3(8, 8), 512, 0, stream>>>(Mh, ssv + l, SB[l & 1], ssv + l + 1, invfac);
    if (l + 1 < NSQ)
      k_h16<<<1024, 256, 0, stream>>>(SB[l & 1], Mh, (1024 * 1024) / 4, 4096.0f);
  }
  float* Mfin = SB[(NSQ - 1) & 1];
  for (int i = 0; i < NPI; i++) {
    const float* xin = (i & 1) ? XB : XA;
    float* xout = (i & 1) ? XA : XB;
    k_matvec<<<256, 256, 0, stream>>>(Mfin, xin, xout,
                                      i ? norms + (i - 1) * 4 : nullptr, norms + i * 4);
  }
  k_rq  <<<256, 256, 0, stream>>>(G, XA, num, den);
  k_finL<<<1, 64, 0, stream>>>(num, den, Lp);

  // deterministic momentum sequence (done-flag can never trigger: ||dC||_F >> 1e-6)
  float tcv[2 * NITER];
  {
    float t = 1.0f;
    for (int i = 0; i < 2 * NITER; i++) {
      float tn = 0.5f * (1.0f + sqrtf(1.0f + 4.0f * t * t));
      tcv[i] = (t - 1.0f) / tn;
      t = tn;
    }
  }

  for (int i = 0; i < 2 * NITER; i++) {
    int a = i & 1, b = (i + 1) & 1;
    if (i == NITER) {
      k_rowss <<<1024, 256, 0, stream>>>(CcB[a], rowss);
      k_thrmat<<<(NB * NP) / 256, 256, 0, stream>>>(CcB[a], rowss, Lp, thrM);
    }
    const float* thr = (i < NITER) ? nullptr : thrM;
    k_mm <<<512, 512, 0, stream>>>(ChB[a], ClB[a], H, Ee, part);
    k_epi<<<(NB * NP) / 1024, 256, 0, stream>>>(part, DtY, CcB[a], ChB[a], ClB[a], Lp, thr,
                                                tcv[i], CcB[b], ChB[b], ClB[b]);
  }
  k_out<<<dim3(32, 16), 256, 0, stream>>>(CcB[0], out);
}